// Round 16
// baseline (109.095 us; speedup 1.0000x reference)
//
#include <hip/hip_runtime.h>
#include <hip/hip_bf16.h>

#define NSPK 1024
#define MU 32
#define DIM 512
#define DIMP (DIM + 8)
#define NROW (NSPK * MU)   // 32768
#define EPS 1e-6f

typedef __attribute__((ext_vector_type(16))) float f32x16;
typedef __attribute__((ext_vector_type(8))) short bf16x8;

#define GLOAD_LDS16(g, l)                                          \
  __builtin_amdgcn_global_load_lds(                                \
      (const __attribute__((address_space(1))) void*)(g),          \
      (__attribute__((address_space(3))) void*)(l), 16, 0, 0)

__device__ inline ushort f2bf(float x) {
  __hip_bfloat16 h = __float2bfloat16(x);
  return *reinterpret_cast<ushort*>(&h);
}

// ---------------------------------------------------------------------------
// Kernel 1: per-speaker prep. LOO cosines (fp32 exact) + normalized bf16
// A and B in 32-WIDE MFMA-FRAGMENT-MAJOR layout for mfma_32x32x16_bf16:
//   frag(rb32, kf16) = 512 ushorts; lane l holds row/col = base32 + (l&31),
//   k = kf*16 + (l>>5)*8 .. +8 (16 B chunk). Speaker j == A-frag-row j.
// grid = NSPK, block = 256
// ---------------------------------------------------------------------------
__global__ __launch_bounds__(256) void k_prep(
    const float* __restrict__ dvecs,
    ushort* __restrict__ Af,    // [1024 rb32][32 kf][64 lane][8]
    ushort* __restrict__ Bf,    // [32 nb32][32 kf][64 lane][8]
    float* __restrict__ loo)    // [NROW]
{
  const int j = blockIdx.x, t = threadIdx.x;
  __shared__ float sD[MU * DIMP];   // padded raw speaker rows (66.5 KiB)
  __shared__ float sS[DIM];
  __shared__ float sred[4];
  __shared__ float sS2v;
  __shared__ float sInv[MU];

  const float* base = dvecs + (size_t)j * (MU * DIM);

  // single global read: stage rows + column sums
  float s0 = 0.f, s1 = 0.f;
  for (int m = 0; m < MU; ++m) {
    float a = base[m * DIM + t];
    float b = base[m * DIM + t + 256];
    sD[m * DIMP + t] = a;
    sD[m * DIMP + t + 256] = b;
    s0 += a; s1 += b;
  }
  sS[t] = s0; sS[t + 256] = s1;
  __syncthreads();

  // |S|^2
  float p = s0 * s0 + s1 * s1;
  for (int off = 32; off; off >>= 1) p += __shfl_down(p, off);
  if ((t & 63) == 0) sred[t >> 6] = p;
  __syncthreads();
  if (t == 0) sS2v = sred[0] + sred[1] + sred[2] + sred[3];
  __syncthreads();
  const float S2 = sS2v;

  // per-utterance dot(e,S), |e|^2 from LDS (8 lanes per row)
  const int g = t >> 3, l = t & 7;
  float dotS = 0.f, e2 = 0.f;
  for (int i = 0; i < DIM / 8; ++i) {
    int d = i * 8 + l;
    float ev = sD[g * DIMP + d];
    dotS += ev * sS[d];
    e2 += ev * ev;
  }
  for (int off = 4; off; off >>= 1) {
    dotS += __shfl_down(dotS, off);
    e2 += __shfl_down(e2, off);
  }
  if (l == 0) {
    float numer = dotS - e2;                          // e.(S-e)
    float d2 = fmaxf(S2 - 2.f * dotS + e2, 1e-30f);   // |S-e|^2
    loo[j * MU + g] = numer / (sqrtf(e2) * sqrtf(d2));
    sInv[g] = 1.f / sqrtf(e2);
  }
  __syncthreads();

  // A fragments: speaker j = rows j*32..+31 = frag-row j; 32 kf chunks.
  for (int i = 0; i < 8; ++i) {
    int idx = i * 256 + t;          // 0..2047 16B-chunks
    int kfg = idx >> 6;             // 0..31
    int lane2 = idx & 63;
    int m = lane2 & 31;
    int k0 = kfg * 16 + (lane2 >> 5) * 8;
    float inv = sInv[m];
    ushort tmp[8];
#pragma unroll
    for (int z = 0; z < 8; ++z) tmp[z] = f2bf(sD[m * DIMP + k0 + z] * inv);
    *(bf16x8*)&Af[(((size_t)j * 32 + kfg) << 9) + lane2 * 8] = *(bf16x8*)tmp;
  }

  // B fragment pieces for centroid j: col-lane = j&31 in frag-col j>>5.
  if (t < 64) {
    int kf = t >> 1, half = t & 1;
    int lane2 = half * 32 + (j & 31);
    float invc = 1.f / sqrtf(S2);
    int k0 = kf * 16 + half * 8;
    ushort tmp[8];
#pragma unroll
    for (int z = 0; z < 8; ++z) tmp[z] = f2bf(sS[k0 + z] * invc);
    *(bf16x8*)&Bf[(((size_t)(j >> 5) * 32 + kf) << 9) + lane2 * 8] =
        *(bf16x8*)tmp;
  }
}

// ---------------------------------------------------------------------------
// Kernel 2: 32x32-MFMA tiled GEMM, 3-buffer counted-vmcnt schedule (R12's).
// Block 128x256, BK=32 (16 K-steps), 256 thr (4 waves, 2wm x 2wn).
// Wave tile 64x128 = 2 rf x 4 cf of 32x32 frags: acc[2][4] f32x16 =
// 128 AGPR + ~90 arch (frag regs halve vs 16x16 at this tile -> avoids
// R14's 264-reg 1-wave/SIMD trap).
// R15 post-mortem: the ~50us plateau is LDS BANDWIDTH (6 MB/CU through
// one shared unit ~= 25-30us) -- geometry, not schedule. This tile cuts
// LDS to 4.5 MB/CU (12 KB reads per 524k FLOP/wave-step) and amortizes
// per-step sync over 2x FLOP; 32x32 MFMA adds ~20% matrix rate.
// Staging 6 loads/thread/step -> vmcnt(6) consume-wait, 2-deep prologue,
// lgkmcnt(0)+sched_barrier at step end (rule #18).
// LDS 3x24 KiB + 1 = 73 KiB -> 2 blocks/CU.
// Grid 1024 = 256 rb x 4 cb, XCD-chunked swizzle (32-rb band per XCD).
// ---------------------------------------------------------------------------
__global__ __launch_bounds__(256, 1) void k_gemm(
    const ushort* __restrict__ Af,
    const ushort* __restrict__ Bf,
    const float* __restrict__ wp,
    float* __restrict__ part,    // [4][NROW] partial sumexp per col-chunk
    float* __restrict__ diag)    // [NROW] raw cos vs own full centroid
{
  __shared__ ushort ldsA[3 * 8 * 512];    // 24 KiB: 3 bufs x 8 frags
  __shared__ ushort ldsB[3 * 16 * 512];   // 48 KiB: 3 bufs x 16 frags
  __shared__ float sPart[128][2];         // 1 KiB

  const int t = threadIdx.x;
  const int w = t >> 6, lane = t & 63;
  const int hi = lane >> 5;               // k-half / row-half selector
  const int wm = w >> 1, wn = w & 1;      // 2 x 2 wave grid
  // XCD-chunked block swizzle
  const int bid = blockIdx.x;
  const int xcd = bid & 7, ii = bid >> 3;     // ii in [0,128) per XCD
  const int rb = xcd * 32 + (ii >> 2);        // 0..255 (128 rows each)
  const int cb = ii & 3;                      // 0..3   (256 cols each)

  f32x16 acc[2][4];
#pragma unroll
  for (int a = 0; a < 2; ++a)
#pragma unroll
    for (int b = 0; b < 4; ++b) acc[a][b] = (f32x16)0.f;

  // staging: 8 A-frags (4 rf32 x 2 kh) + 16 B-frags (8 cf32 x 2 kh) per
  // step; wave w stages rf32=w (2 loads) and cf32={w, w+4} (4 loads).
  const ushort* gA  = Af + (((size_t)(rb * 4 + w) * 32) << 9) + lane * 8;
  const ushort* gB0 = Bf + (((size_t)(cb * 8 + w) * 32) << 9) + lane * 8;
  const ushort* gB1 = Bf + (((size_t)(cb * 8 + w + 4) * 32) << 9) + lane * 8;
  ushort* dA0 = &ldsA[(w * 2) * 512 + lane * 8];
  ushort* dA1 = &ldsA[(w * 2 + 1) * 512 + lane * 8];
  ushort* dB0 = &ldsB[(w * 2) * 512 + lane * 8];
  ushort* dB1 = &ldsB[(w * 2 + 1) * 512 + lane * 8];
  ushort* dB2 = &ldsB[((w + 4) * 2) * 512 + lane * 8];
  ushort* dB3 = &ldsB[((w + 4) * 2 + 1) * 512 + lane * 8];

#define STAGE(kt, bi)                                       \
  {                                                         \
    GLOAD_LDS16(gA + (2 * (kt)) * 512, dA0 + (bi) * 4096);  \
    GLOAD_LDS16(gA + (2 * (kt) + 1) * 512, dA1 + (bi) * 4096); \
    GLOAD_LDS16(gB0 + (2 * (kt)) * 512, dB0 + (bi) * 8192); \
    GLOAD_LDS16(gB0 + (2 * (kt) + 1) * 512, dB1 + (bi) * 8192); \
    GLOAD_LDS16(gB1 + (2 * (kt)) * 512, dB2 + (bi) * 8192); \
    GLOAD_LDS16(gB1 + (2 * (kt) + 1) * 512, dB3 + (bi) * 8192); \
  }

  // fragment read bases: A frag (wm*2+rf)*2+kh ; B frag (wn*4+cf)*2+kh
  const ushort* lA0 = &ldsA[(wm * 2) * 1024 + lane * 8];
  const ushort* lB0 = &ldsB[(wn * 4) * 1024 + lane * 8];

  // ---- prologue: 2-deep stage prefetch (12 loads/thread in flight) ----
  STAGE(0, 0);
  STAGE(1, 1);

  // ---- pipelined K-loop ----
#pragma unroll
  for (int kt = 0; kt < 16; ++kt) {
    if (kt < 15) {
      asm volatile("s_waitcnt vmcnt(6)" ::: "memory");  // stage(kt) landed
    } else {
      asm volatile("s_waitcnt vmcnt(0)" ::: "memory");
    }
    __builtin_amdgcn_s_barrier();
    __builtin_amdgcn_sched_barrier(0);

    if (kt <= 13) STAGE(kt + 2, (kt + 2) % 3);

    const ushort* lA = lA0 + (kt % 3) * 4096;
    const ushort* lB = lB0 + (kt % 3) * 8192;
#pragma unroll
    for (int kh = 0; kh < 2; ++kh) {
      bf16x8 afr[2], bfr[4];
#pragma unroll
      for (int cf = 0; cf < 4; ++cf)
        bfr[cf] = *(const bf16x8*)(lB + (cf * 2 + kh) * 512);
#pragma unroll
      for (int rf = 0; rf < 2; ++rf)
        afr[rf] = *(const bf16x8*)(lA + (rf * 2 + kh) * 512);

      __builtin_amdgcn_s_setprio(1);
#pragma unroll
      for (int rf = 0; rf < 2; ++rf)
#pragma unroll
        for (int cf = 0; cf < 4; ++cf)
          acc[rf][cf] = __builtin_amdgcn_mfma_f32_32x32x16_bf16(
              afr[rf], bfr[cf], acc[rf][cf], 0, 0, 0);
      __builtin_amdgcn_s_setprio(0);
    }

    if (kt < 15) {
      asm volatile("s_waitcnt lgkmcnt(0)" ::: "memory");  // buf safety
      __builtin_amdgcn_sched_barrier(0);
    }
  }
#undef STAGE

  const float W = *wp;

  // ---- diag capture (raw cos) before exp consumes acc ----
  // C/D layout (32x32): col = lane&31, row = (i&3)+8*(i>>2)+4*hi.
  // Block speakers sp=0..3: col c = rb*4+sp, in block iff cb == c>>8;
  // rows of sp live in rf32 = sp -> wave wm = sp>>1, rf = sp&1.
  if (cb == (rb >> 6)) {
#pragma unroll
    for (int sp = 0; sp < 4; ++sp) {
      const int c = rb * 4 + sp;
      if (wm == (sp >> 1) && wn == ((c >> 7) & 1)) {
        const int nfo = (c >> 5) & 3;
        f32x16 dsel = acc[sp & 1][0];
#pragma unroll
        for (int cf = 1; cf < 4; ++cf)
          if (cf == nfo) dsel = acc[sp & 1][cf];   // static idx only
        if ((lane & 31) == (c & 31)) {
#pragma unroll
          for (int i = 0; i < 16; ++i)
            diag[c * 32 + (i & 3) + 8 * (i >> 2) + 4 * hi] = dsel[i];
        }
      }
    }
  }

  // ---- fused epilogue: exp((fmax(cos,eps)-1)*W), reduce over 128 cols ----
#pragma unroll
  for (int rf = 0; rf < 2; ++rf)
#pragma unroll
    for (int i = 0; i < 16; ++i) {
      float s = 0.f;
#pragma unroll
      for (int cf = 0; cf < 4; ++cf)
        s += __expf((fmaxf(acc[rf][cf][i], EPS) - 1.f) * W);
      // reduce over the 32 cols (lanes within each 32-lane half)
      s += __shfl_xor(s, 1);
      s += __shfl_xor(s, 2);
      s += __shfl_xor(s, 4);
      s += __shfl_xor(s, 8);
      s += __shfl_xor(s, 16);
      if ((lane & 31) == 0)
        sPart[wm * 64 + rf * 32 + (i & 3) + 8 * (i >> 2) + 4 * hi][wn] = s;
    }
  __syncthreads();
  if (t < 128)
    part[(size_t)cb * NROW + rb * 128 + t] = sPart[t][0] + sPart[t][1];
}

// ---------------------------------------------------------------------------
// Final: sum 4 col-chunk partials, swap exp(diag)->exp(loo), close lse,
// deterministic 2-stage sum.  L_row = log(s - exp(dt) + exp(lt)) - lt
// ---------------------------------------------------------------------------
__global__ __launch_bounds__(256) void k_final1(
    const float* __restrict__ part, const float* __restrict__ loo,
    const float* __restrict__ diag, const float* __restrict__ wp,
    float* __restrict__ p2)
{
  const int t = threadIdx.x;
  const int r = blockIdx.x * 256 + t;
  const float W = *wp;
  float s = 0.f;
#pragma unroll
  for (int c = 0; c < 4; ++c) s += part[(size_t)c * NROW + r];
  const float lt = (fmaxf(loo[r], EPS) - 1.f) * W;
  const float dt = (fmaxf(diag[r], EPS) - 1.f) * W;
  s += __expf(lt) - __expf(dt);
  float v = logf(s) - lt;
  __shared__ float red[4];
  for (int off = 32; off; off >>= 1) v += __shfl_down(v, off);
  if ((t & 63) == 0) red[t >> 6] = v;
  __syncthreads();
  if (t == 0) p2[blockIdx.x] = red[0] + red[1] + red[2] + red[3];
}

__global__ __launch_bounds__(128) void k_final2(
    const float* __restrict__ p2, float* __restrict__ out)
{
  const int t = threadIdx.x;
  float v = p2[t];
  for (int off = 32; off; off >>= 1) v += __shfl_down(v, off);
  __shared__ float red[2];
  if ((t & 63) == 0) red[t >> 6] = v;
  __syncthreads();
  if (t == 0) out[0] = red[0] + red[1];
}

extern "C" void kernel_launch(void* const* d_in, const int* in_sizes, int n_in,
                              void* d_out, int out_size, void* d_ws, size_t ws_size,
                              hipStream_t stream) {
  const float* dvecs = (const float*)d_in[0];
  const float* wptr  = (const float*)d_in[1];
  // b cancels algebraically (shift = w+b subtracted and re-added) -> unused
  float* out = (float*)d_out;

  char* ws = (char*)d_ws;
  ushort* Af = (ushort*)ws;  ws += (size_t)NROW * DIM * sizeof(ushort); // 32 MiB
  ushort* Bf = (ushort*)ws;  ws += (size_t)NSPK * DIM * sizeof(ushort); // 1 MiB
  float* loo  = (float*)ws;  ws += (size_t)NROW * sizeof(float);
  float* diag = (float*)ws;  ws += (size_t)NROW * sizeof(float);
  float* part = (float*)ws;  ws += (size_t)4 * NROW * sizeof(float);    // 512 KiB
  float* p2   = (float*)ws;

  k_prep<<<NSPK, 256, 0, stream>>>(dvecs, Af, Bf, loo);
  k_gemm<<<1024, 256, 0, stream>>>(Af, Bf, wptr, part, diag);
  k_final1<<<NROW / 256, 256, 0, stream>>>(part, loo, diag, wptr, p2);
  k_final2<<<1, 128, 0, stream>>>(p2, out);
}